// Round 1
// 1252.482 us; speedup vs baseline: 1.3105x; 1.3105x over previous
//
#include <hip/hip_runtime.h>

#define NEG_SLOPE 0.01f
#define MAXDEG_LDS 256

// ---- zero CSR counters + cursor ----
__global__ void init_kernel(int* __restrict__ cnt, int* __restrict__ cursor, int N) {
  const int gid = blockIdx.x * 256 + threadIdx.x;
  if (gid < N) cnt[gid] = 0;
  if (gid == 0) *cursor = 0;
}

// ---- h_t = nfeats @ W_nodes + b_nodes  -> ws_ht [N,128] ----
__global__ __launch_bounds__(256) void node_kernel(
    const float* __restrict__ nfeats, const float* __restrict__ W_nodes,
    const float* __restrict__ b_nodes, float* __restrict__ ht, int N) {
  const int gid = blockIdx.x * 256 + threadIdx.x;
  if (gid >= N * 128) return;
  const int n = gid >> 7, c = gid & 127;
  float acc = b_nodes[c];
  const float* nrow = nfeats + n * 64;
#pragma unroll 8
  for (int k = 0; k < 64; ++k) acc += nrow[k] * W_nodes[k * 128 + c];
  ht[gid] = acc;
}

// ---- edge GEMM: f_out = leaky_relu(stack @ W_edges + b); a = f_out . w_sum ----
// Tile: 64 edges x 128 cols per block of 256 threads.
// Thread (tx=tid&31, ty=tid>>5): 8 edges (rows 8ty..8ty+7) x 4 cols (4tx..4tx+3).
// 32 FMA per W float4 load; launch_bounds(256,3) matches the LDS cap (3 blocks/CU)
// and frees the register allocator to keep unroll-4's W loads in flight.
__global__ __launch_bounds__(256, 3) void edge_kernel(
    const float* __restrict__ nfeats, const float* __restrict__ efeats,
    const int* __restrict__ src, const int* __restrict__ dst,
    const float* __restrict__ W_edges, const float* __restrict__ b_edges,
    const float* __restrict__ W_attn,
    float* __restrict__ fout, float* __restrict__ a_out, int E) {
  __shared__ float s_stack[64 * 196];  // stride 196 breaks bank aliasing
  const int tid = threadIdx.x;
  const int e0 = blockIdx.x * 64;

  // stage [src(64)|efeats(64)|dst(64)] per edge row; 4 threads/row, 12 float4 each
  {
    const int row = tid >> 2;   // 0..63
    const int j = tid & 3;      // 0..3
    const int e = e0 + row;
    if (e < E) {
      const int se = src[e], de = dst[e];
      const float4* nf4 = (const float4*)nfeats;
      const float4* ef4 = (const float4*)efeats;
      float4* out4 = (float4*)(&s_stack[row * 196]);
#pragma unroll
      for (int i = 0; i < 12; ++i) {
        const int q = j + i * 4;  // 0..47
        float4 v;
        if (q < 16)      v = nf4[se * 16 + q];
        else if (q < 32) v = ef4[(size_t)e * 16 + (q - 16)];
        else             v = nf4[de * 16 + (q - 32)];
        out4[q] = v;
      }
    }
  }
  __syncthreads();

  const int tx = tid & 31;
  const int ty = tid >> 5;   // 0..7

  float4 acc[8];
#pragma unroll
  for (int i = 0; i < 8; ++i) acc[i] = make_float4(0.f, 0.f, 0.f, 0.f);

  const float4* __restrict__ W4 = (const float4*)W_edges;   // row k -> 32 float4
  const float* __restrict__ s_base = &s_stack[ty * 8 * 196];

#pragma unroll 4
  for (int k = 0; k < 192; ++k) {
    const float4 w = W4[k * 32 + tx];
#pragma unroll
    for (int r = 0; r < 8; ++r) {
      const float s = s_base[r * 196 + k];  // ds_read_b32, imm offset, 2-addr broadcast
      acc[r].x += s * w.x;
      acc[r].y += s * w.y;
      acc[r].z += s * w.z;
      acc[r].w += s * w.w;
    }
  }

  // epilogue: bias, leaky_relu, store f_out, attention logit reduce (no atomicMax)
  const float4 bias = ((const float4*)b_edges)[tx];
  const int cbase = 4 * tx;
  float wsum[4];
#pragma unroll
  for (int j = 0; j < 4; ++j) {
    const int f = (cbase + j) & 31;
    wsum[j] = W_attn[f * 4 + 0] + W_attn[f * 4 + 1] + W_attn[f * 4 + 2] + W_attn[f * 4 + 3];
  }
  const int head = tx >> 3;
  float4* fout4 = (float4*)fout;

#pragma unroll
  for (int r = 0; r < 8; ++r) {
    const int e = e0 + ty * 8 + r;
    float4 v = acc[r];
    v.x += bias.x; v.y += bias.y; v.z += bias.z; v.w += bias.w;
    v.x = v.x >= 0.f ? v.x : NEG_SLOPE * v.x;
    v.y = v.y >= 0.f ? v.y : NEG_SLOPE * v.y;
    v.z = v.z >= 0.f ? v.z : NEG_SLOPE * v.z;
    v.w = v.w >= 0.f ? v.w : NEG_SLOPE * v.w;
    if (e < E) fout4[(size_t)e * 32 + tx] = v;
    float pa = v.x * wsum[0] + v.y * wsum[1] + v.z * wsum[2] + v.w * wsum[3];
    pa += __shfl_xor(pa, 1);
    pa += __shfl_xor(pa, 2);
    pa += __shfl_xor(pa, 4);
    if ((tx & 7) == 0 && e < E) a_out[(size_t)e * 4 + head] = pa;
  }
}

// ---- CSR build: count -> offsets (atomic cursor; arbitrary but consistent order) -> fill ----
__global__ void csr_count_kernel(const int* __restrict__ dst, int* __restrict__ cnt, int E) {
  const int gid = blockIdx.x * 256 + threadIdx.x;
  if (gid < E) atomicAdd(&cnt[dst[gid]], 1);
}

__global__ void csr_offset_kernel(int* __restrict__ start, int* __restrict__ fill,
                                  int* __restrict__ cursor, int N) {
  const int gid = blockIdx.x * 256 + threadIdx.x;
  if (gid < N) {
    const int c = start[gid];          // start[] currently holds counts
    const int s = atomicAdd(cursor, c);
    start[gid] = s;
    fill[gid] = s;
  }
}

__global__ void csr_fill_kernel(const int* __restrict__ dst, int* __restrict__ fill,
                                int* __restrict__ eidx, int E) {
  const int gid = blockIdx.x * 256 + threadIdx.x;
  if (gid < E) {
    const int slot = atomicAdd(&fill[dst[gid]], 1);
    eidx[slot] = gid;
  }
  // post: fill[n] == start[n] + deg[n]  (segment end)
}

// ---- per-dst-node fused softmax + gather: one wave per node, zero atomics ----
// lane l owns channels (2l, 2l+1); head = (2l)>>5 = l>>4.
__global__ __launch_bounds__(64) void gather_kernel(
    const int* __restrict__ eidx, const int* __restrict__ start,
    const int* __restrict__ fin, const int* __restrict__ src,
    const float* __restrict__ a, const float* __restrict__ ht,
    float* __restrict__ hout, int N) {
  __shared__ float s_w[MAXDEG_LDS * 4];
  __shared__ int s_src[MAXDEG_LDS];
  const int n = blockIdx.x;
  const int l = threadIdx.x;
  const int s0 = start[n];
  const int deg = fin[n] - s0;
  float2 acc = make_float2(0.f, 0.f);

  if (deg > 0) {
    const float4* a4 = (const float4*)a;
    // phase 1: per-head max over incoming edges
    float4 m = make_float4(-1e30f, -1e30f, -1e30f, -1e30f);
    for (int i = l; i < deg; i += 64) {
      const float4 av = a4[eidx[s0 + i]];
      m.x = fmaxf(m.x, av.x); m.y = fmaxf(m.y, av.y);
      m.z = fmaxf(m.z, av.z); m.w = fmaxf(m.w, av.w);
    }
#pragma unroll
    for (int off = 32; off > 0; off >>= 1) {
      m.x = fmaxf(m.x, __shfl_xor(m.x, off));
      m.y = fmaxf(m.y, __shfl_xor(m.y, off));
      m.z = fmaxf(m.z, __shfl_xor(m.z, off));
      m.w = fmaxf(m.w, __shfl_xor(m.w, off));
    }
    // phase 2: unnormalized exp + denom; stash weights & src ids in LDS
    float4 dsum = make_float4(0.f, 0.f, 0.f, 0.f);
    for (int i = l; i < deg; i += 64) {
      const int e = eidx[s0 + i];
      const float4 av = a4[e];
      const float ex0 = __expf(av.x - m.x);
      const float ex1 = __expf(av.y - m.y);
      const float ex2 = __expf(av.z - m.z);
      const float ex3 = __expf(av.w - m.w);
      dsum.x += ex0; dsum.y += ex1; dsum.z += ex2; dsum.w += ex3;
      if (i < MAXDEG_LDS) {
        s_w[i * 4 + 0] = ex0; s_w[i * 4 + 1] = ex1;
        s_w[i * 4 + 2] = ex2; s_w[i * 4 + 3] = ex3;
        s_src[i] = src[e];
      }
    }
#pragma unroll
    for (int off = 32; off > 0; off >>= 1) {
      dsum.x += __shfl_xor(dsum.x, off);
      dsum.y += __shfl_xor(dsum.y, off);
      dsum.z += __shfl_xor(dsum.z, off);
      dsum.w += __shfl_xor(dsum.w, off);
    }
    const int head = l >> 4;
    const float mh = (head == 0 ? m.x : head == 1 ? m.y : head == 2 ? m.z : m.w);
    const float rh = 1.0f / (head == 0 ? dsum.x : head == 1 ? dsum.y :
                             head == 2 ? dsum.z : dsum.w);
    const float2* ht2 = (const float2*)ht;
    // phase 3: weighted accumulation, register-resident, no atomics
    for (int i = 0; i < deg; ++i) {
      float wgt; int sn;
      if (i < MAXDEG_LDS) {
        wgt = s_w[i * 4 + head] * rh;   // broadcast ds_read
        sn = s_src[i];
      } else {  // cold fallback for pathological degree
        const int e = eidx[s0 + i];
        const float4 av = a4[e];
        const float ah = (head == 0 ? av.x : head == 1 ? av.y :
                          head == 2 ? av.z : av.w);
        wgt = __expf(ah - mh) * rh;
        sn = src[e];
      }
      const float2 hv = ht2[(size_t)sn * 64 + l];  // coalesced 512B row
      acc.x += wgt * hv.x;
      acc.y += wgt * hv.y;
    }
  }
  ((float2*)hout)[(size_t)n * 64 + l] = acc;
}

extern "C" void kernel_launch(void* const* d_in, const int* in_sizes, int n_in,
                              void* d_out, int out_size, void* d_ws, size_t ws_size,
                              hipStream_t stream) {
  const float* nfeats  = (const float*)d_in[0];
  const float* efeats  = (const float*)d_in[1];
  const int*   src     = (const int*)d_in[2];
  const int*   dst     = (const int*)d_in[3];
  const float* W_nodes = (const float*)d_in[4];
  const float* b_nodes = (const float*)d_in[5];
  const float* W_edges = (const float*)d_in[6];
  const float* b_edges = (const float*)d_in[7];
  const float* W_attn  = (const float*)d_in[8];

  const int N = in_sizes[0] / 64;
  const int E = in_sizes[2];

  // workspace layout: ht[N*128] f32 | a[E*4] f32 | start[N] i32 | fill[N] i32 | eidx[E] i32 | cursor[1]
  float* ws = (float*)d_ws;
  float* ht = ws;
  float* a  = ws + (size_t)N * 128;
  int* start  = (int*)(a + (size_t)E * 4);
  int* fill   = start + N;
  int* eidx   = fill + N;
  int* cursor = eidx + E;

  float* hout = (float*)d_out;                    // [N,4,32]
  float* fout = hout + (size_t)N * 128;           // [E,4,32]

  init_kernel<<<(N + 255) / 256, 256, 0, stream>>>(start, cursor, N);
  node_kernel<<<(N * 128 + 255) / 256, 256, 0, stream>>>(nfeats, W_nodes, b_nodes, ht, N);
  edge_kernel<<<(E + 63) / 64, 256, 0, stream>>>(nfeats, efeats, src, dst, W_edges,
                                                 b_edges, W_attn, fout, a, E);
  csr_count_kernel<<<(E + 255) / 256, 256, 0, stream>>>(dst, start, E);
  csr_offset_kernel<<<(N + 255) / 256, 256, 0, stream>>>(start, fill, cursor, N);
  csr_fill_kernel<<<(E + 255) / 256, 256, 0, stream>>>(dst, fill, eidx, E);
  gather_kernel<<<N, 64, 0, stream>>>(eidx, start, fill, src, a, ht, hout, N);
}